// Round 4
// baseline (686.075 us; speedup 1.0000x reference)
//
#include <hip/hip_runtime.h>
#include <hip/hip_bf16.h>

#define NEG_SLOPE 0.01f

typedef long long i64;
typedef __hip_bfloat16 bf16;

__device__ __forceinline__ float lrelu(float x) { return x > 0.f ? x : NEG_SLOPE * x; }
__device__ __forceinline__ float b2f(bf16 v) { return __bfloat162float(v); }
__device__ __forceinline__ float lo2f(unsigned u) { return __uint_as_float(u << 16); }
__device__ __forceinline__ float hi2f(unsigned u) { return __uint_as_float(u & 0xffff0000u); }
__device__ __forceinline__ unsigned pk2(float a, float b) {
    unsigned ua = __bfloat16_as_ushort(__float2bfloat16(a));
    unsigned ub = __bfloat16_as_ushort(__float2bfloat16(b));
    return ua | (ub << 16);
}
__device__ __forceinline__ void acc8(float* h, uint4 u) {
    h[0] += lo2f(u.x); h[1] += hi2f(u.x);
    h[2] += lo2f(u.y); h[3] += hi2f(u.y);
    h[4] += lo2f(u.z); h[5] += hi2f(u.z);
    h[6] += lo2f(u.w); h[7] += hi2f(u.w);
}

// ================= degree / dinv (batch-independent) =================
__global__ __launch_bounds__(256) void k_deg(const int* __restrict__ edges,
                                             int* __restrict__ indeg, int E) {
    int e = blockIdx.x * 256 + threadIdx.x;
    if (e < E) atomicAdd(&indeg[edges[2 * e + 1]], 1);
}

__global__ __launch_bounds__(256) void k_dinv(const int* __restrict__ indeg,
                                              float* __restrict__ dinv, int V) {
    int v = blockIdx.x * 256 + threadIdx.x;
    if (v < V) dinv[v] = rsqrtf((float)indeg[v] + 1.0f);
}

// ================= CSR build: exclusive scan of indeg + fill =================
__global__ __launch_bounds__(256) void k_scan1(const int* __restrict__ indeg,
                                               int* __restrict__ rowptr,
                                               int* __restrict__ bsum, int V) {
    __shared__ int s[256];
    int i = blockIdx.x * 256 + threadIdx.x;
    int x = (i < V) ? indeg[i] : 0;
    s[threadIdx.x] = x;
    __syncthreads();
    for (int off = 1; off < 256; off <<= 1) {
        int t = (threadIdx.x >= (unsigned)off) ? s[threadIdx.x - off] : 0;
        __syncthreads();
        s[threadIdx.x] += t;
        __syncthreads();
    }
    if (i < V) rowptr[i] = s[threadIdx.x] - x;  // exclusive within block
    if (threadIdx.x == 255) bsum[blockIdx.x] = s[255];
}

__global__ __launch_bounds__(1024) void k_scan2(int* __restrict__ bsum, int NB) {
    __shared__ int s[1024];
    __shared__ int srun;
    if (threadIdx.x == 0) srun = 0;
    __syncthreads();
    for (int base = 0; base < NB; base += 1024) {
        int i = base + threadIdx.x;
        int x = (i < NB) ? bsum[i] : 0;
        s[threadIdx.x] = x;
        __syncthreads();
        for (int off = 1; off < 1024; off <<= 1) {
            int t = (threadIdx.x >= (unsigned)off) ? s[threadIdx.x - off] : 0;
            __syncthreads();
            s[threadIdx.x] += t;
            __syncthreads();
        }
        int run = srun;
        if (i < NB) bsum[i] = run + s[threadIdx.x] - x;  // exclusive
        __syncthreads();
        if (threadIdx.x == 1023) srun = run + s[1023];
        __syncthreads();
    }
}

__global__ __launch_bounds__(256) void k_scan3(int* __restrict__ rowptr,
                                               const int* __restrict__ bsum,
                                               int V, int E) {
    int i = blockIdx.x * 256 + threadIdx.x;
    if (i < V) rowptr[i] += bsum[blockIdx.x];
    if (i == 0) rowptr[V] = E;
}

__global__ __launch_bounds__(256) void k_fill(const int* __restrict__ edges,
                                              const int* __restrict__ rowptr,
                                              int* __restrict__ cur,
                                              int* __restrict__ col, int E) {
    int e = blockIdx.x * 256 + threadIdx.x;
    if (e >= E) return;
    int s = edges[2 * e], d = edges[2 * e + 1];
    int p = atomicAdd(&cur[d], 1);
    col[rowptr[d] + p] = s;
}

// ========== H==16: fused layer1+layer2, 4 batches/thread ==========
// Layer-1 linearity: h1_pre = di * ((Σ_{u∈{v}∪N(v)} du·x_u) @ W1)
__global__ __launch_bounds__(256) void k_gl12(const int* __restrict__ rowptr,
                                              const int* __restrict__ col,
                                              const float* __restrict__ verts,
                                              const float* __restrict__ W1,
                                              const float* __restrict__ b1,
                                              const float* __restrict__ W2,
                                              const float* __restrict__ dinv,
                                              bf16* __restrict__ PB,
                                              float* __restrict__ Q,
                                              int b0, int V, int CBc) {
    int v = blockIdx.x * 256 + threadIdx.x;
    if (v >= V) return;
    int bg0 = blockIdx.y * 4;
    int nb = CBc - bg0; if (nb > 4) nb = 4;
    float di = dinv[v];
    // clamped global batch index per slot (branch-free OOB safety)
    i64 gvb[4];
#pragma unroll
    for (int mb = 0; mb < 4; ++mb) {
        int mbc = mb < nb ? mb : nb - 1;
        gvb[mb] = (i64)(b0 + bg0 + mbc) * V;
    }
    float c[4][3];
#pragma unroll
    for (int mb = 0; mb < 4; ++mb) {
        const float* xv = verts + (gvb[mb] + v) * 3;
        c[mb][0] = di * xv[0]; c[mb][1] = di * xv[1]; c[mb][2] = di * xv[2];
    }
    int r0 = rowptr[v], r1 = rowptr[v + 1];
    for (int j = r0; j < r1; ++j) {
        int s = col[j];
        float ds = dinv[s];
#pragma unroll
        for (int mb = 0; mb < 4; ++mb) {
            const float* xs = verts + (gvb[mb] + s) * 3;
            c[mb][0] += ds * xs[0]; c[mb][1] += ds * xs[1]; c[mb][2] += ds * xs[2];
        }
    }
#pragma unroll
    for (int mb = 0; mb < 4; ++mb) {
        if (mb >= nb) break;
        float h[16];
#pragma unroll
        for (int f = 0; f < 16; ++f)
            h[f] = lrelu(di * (c[mb][0] * W1[f] + c[mb][1] * W1[16 + f] +
                               c[mb][2] * W1[32 + f]) + b1[f]);
        float g[16];
#pragma unroll
        for (int f = 0; f < 16; ++f) g[f] = 0.f;
#pragma unroll
        for (int k = 0; k < 16; ++k) {
            float hk = h[k];
#pragma unroll
            for (int f = 0; f < 16; ++f) g[f] += hk * W2[k * 16 + f];
        }
#pragma unroll
        for (int f = 0; f < 16; ++f) g[f] *= di;
        i64 m = (i64)(bg0 + mb) * V + v;
        uint4* Pp = (uint4*)(PB + m * 16);
        Pp[0] = make_uint4(pk2(g[0], g[1]), pk2(g[2], g[3]), pk2(g[4], g[5]), pk2(g[6], g[7]));
        Pp[1] = make_uint4(pk2(g[8], g[9]), pk2(g[10], g[11]), pk2(g[12], g[13]), pk2(g[14], g[15]));
        float4* Qp = (float4*)(Q + m * 16);
#pragma unroll
        for (int q = 0; q < 4; ++q)
            Qp[q] = make_float4(g[4 * q], g[4 * q + 1], g[4 * q + 2], g[4 * q + 3]);
    }
}

// ========== H==16: fused gather + layer3 (16 -> 3), 4 batches/thread ==========
__global__ __launch_bounds__(256) void k_gl3(const int* __restrict__ rowptr,
                                             const int* __restrict__ col,
                                             const float* __restrict__ W3,
                                             const float* __restrict__ b2,
                                             const float* __restrict__ dinv,
                                             const bf16* __restrict__ Pin,
                                             const float* __restrict__ Q,
                                             float* __restrict__ R,
                                             int V, int CBc) {
    int v = blockIdx.x * 256 + threadIdx.x;
    if (v >= V) return;
    int bg0 = blockIdx.y * 4;
    int nb = CBc - bg0; if (nb > 4) nb = 4;
    i64 vb[4];
#pragma unroll
    for (int mb = 0; mb < 4; ++mb) {
        int mbc = mb < nb ? mb : nb - 1;
        vb[mb] = (i64)(bg0 + mbc) * V;
    }
    float h[4][16];
#pragma unroll
    for (int mb = 0; mb < 4; ++mb) {
        const float4* Qin = (const float4*)(Q + (vb[mb] + v) * 16);
#pragma unroll
        for (int q = 0; q < 4; ++q) {
            float4 t = Qin[q];
            h[mb][4 * q] = t.x; h[mb][4 * q + 1] = t.y;
            h[mb][4 * q + 2] = t.z; h[mb][4 * q + 3] = t.w;
        }
    }
    int r0 = rowptr[v], r1 = rowptr[v + 1];
    for (int j = r0; j < r1; ++j) {
        size_t u = (size_t)col[j] * 2;
#pragma unroll
        for (int mb = 0; mb < 4; ++mb) {
            const uint4* Pb = (const uint4*)(Pin + vb[mb] * 16);
            uint4 q0 = Pb[u], q1 = Pb[u + 1];
            acc8(h[mb], q0); acc8(h[mb] + 8, q1);
        }
    }
    float di = dinv[v];
#pragma unroll
    for (int mb = 0; mb < 4; ++mb) {
        if (mb >= nb) break;
        float g0 = 0.f, g1 = 0.f, g2 = 0.f;
#pragma unroll
        for (int k = 0; k < 16; ++k) {
            float hk = lrelu(di * h[mb][k] + b2[k]);
            g0 += hk * W3[k * 3 + 0];
            g1 += hk * W3[k * 3 + 1];
            g2 += hk * W3[k * 3 + 2];
        }
        ((float4*)R)[vb[mb] + v] = make_float4(di * g0, di * g1, di * g2, 0.f);
    }
}

// fused gather + final vertex update, 4 batches/thread.
__global__ __launch_bounds__(256) void k_gvert(const int* __restrict__ rowptr,
                                               const int* __restrict__ col,
                                               const float* __restrict__ x,
                                               const float* __restrict__ b3,
                                               const float* __restrict__ dinv,
                                               const float* __restrict__ R,
                                               float* __restrict__ Vpos,
                                               float* __restrict__ out0,
                                               int b0, int V, int E, int CBc) {
    int v = blockIdx.x * 256 + threadIdx.x;
    if (v >= V) return;
    int bg0 = blockIdx.y * 4;
    int nb = CBc - bg0; if (nb > 4) nb = 4;
    i64 vb[4];
#pragma unroll
    for (int mb = 0; mb < 4; ++mb) {
        int mbc = mb < nb ? mb : nb - 1;
        vb[mb] = (i64)(bg0 + mbc) * V;
    }
    float4 s[4];
#pragma unroll
    for (int mb = 0; mb < 4; ++mb) s[mb] = ((const float4*)R)[vb[mb] + v];
    int r0 = rowptr[v], r1 = rowptr[v + 1];
    for (int j = r0; j < r1; ++j) {
        int cs = col[j];
#pragma unroll
        for (int mb = 0; mb < 4; ++mb) {
            float4 t = ((const float4*)R)[vb[mb] + cs];
            s[mb].x += t.x; s[mb].y += t.y; s[mb].z += t.z;
        }
    }
    float di = dinv[v];
#pragma unroll
    for (int mb = 0; mb < 4; ++mb) {
        if (mb >= nb) break;
        int bg = b0 + bg0 + mb;
        i64 n = (i64)bg * V + v;
        float p0 = x[n * 3]     + di * s[mb].x + b3[0];
        float p1 = x[n * 3 + 1] + di * s[mb].y + b3[1];
        float p2 = x[n * 3 + 2] + di * s[mb].z + b3[2];
        ((float4*)Vpos)[vb[mb] + v] = make_float4(p0, p1, p2, 0.f);
        i64 o = ((i64)bg * (V + E) + v) * 3;
        __builtin_nontemporal_store(p0, out0 + o);
        __builtin_nontemporal_store(p1, out0 + o + 1);
        __builtin_nontemporal_store(p2, out0 + o + 2);
    }
}

__global__ __launch_bounds__(256) void k_mid(const int* __restrict__ edges,
                                             const float* __restrict__ Vpos,
                                             float* __restrict__ out0,
                                             int b0, int V, int E, int CBc) {
    int e = blockIdx.x * 256 + threadIdx.x;
    if (e >= E) return;
    int bg0 = blockIdx.y * 4;
    int nb = CBc - bg0; if (nb > 4) nb = 4;
    int s = edges[2 * e], d = edges[2 * e + 1];
#pragma unroll
    for (int mb = 0; mb < 4; ++mb) {
        if (mb >= nb) break;
        i64 vb = (i64)(bg0 + mb) * V;
        float4 ps = ((const float4*)Vpos)[vb + s];
        float4 pd = ((const float4*)Vpos)[vb + d];
        i64 o = ((i64)(b0 + bg0 + mb) * (V + E) + V + e) * 3;
        __builtin_nontemporal_store(0.5f * (ps.x + pd.x), out0 + o);
        __builtin_nontemporal_store(0.5f * (ps.y + pd.y), out0 + o + 1);
        __builtin_nontemporal_store(0.5f * (ps.z + pd.z), out0 + o + 2);
    }
}

__global__ __launch_bounds__(256) void k_faces(const int* __restrict__ faces,
                                               float* __restrict__ out1,
                                               i64 F3, i64 faceElems) {
    i64 i = (i64)blockIdx.x * 256 + threadIdx.x;
    if (i >= F3) return;
    i64 o = (i64)blockIdx.y * F3 + i;
    if (o < faceElems) __builtin_nontemporal_store((float)faces[i], out1 + o);
}

// ================= generic H path (correctness fallback, H <= 64) =================
__global__ __launch_bounds__(256) void k_l1_g(const float* __restrict__ x,
                                              const float* __restrict__ W1,
                                              const float* __restrict__ dinv,
                                              bf16* __restrict__ P, float* __restrict__ Q,
                                              int b0, int V, int H) {
    extern __shared__ float sW[];
    for (int i = threadIdx.x; i < 3 * H; i += 256) sW[i] = W1[i];
    __syncthreads();
    int v = blockIdx.x * 256 + threadIdx.x;
    if (v >= V) return;
    i64 n = (i64)(b0 + blockIdx.y) * V + v;
    i64 m = (i64)blockIdx.y * V + v;
    float di = dinv[v];
    float x0 = x[n * 3], x1 = x[n * 3 + 1], x2 = x[n * 3 + 2];
    for (int f = 0; f < H; ++f) {
        float g = di * (x0 * sW[f] + x1 * sW[H + f] + x2 * sW[2 * H + f]);
        P[m * H + f] = __float2bfloat16(g);
        Q[m * H + f] = g;
    }
}

__global__ __launch_bounds__(256) void k_scatter_g(const int* __restrict__ edges,
                                                   const bf16* __restrict__ P,
                                                   float* __restrict__ Q,
                                                   int E, int V, int H) {
    int e = blockIdx.x * 256 + threadIdx.x;
    if (e >= E) return;
    int b = blockIdx.y;
    int s = edges[2 * e], d = edges[2 * e + 1];
    for (int f = 0; f < H; ++f)
        unsafeAtomicAdd(&Q[((i64)b * V + d) * H + f], b2f(P[((i64)b * V + s) * H + f]));
}

__global__ __launch_bounds__(256) void k_l2_g(const float* __restrict__ W2,
                                              const float* __restrict__ b1,
                                              const float* __restrict__ dinv,
                                              bf16* __restrict__ P, float* __restrict__ Q,
                                              int V, int H) {
    extern __shared__ float sW[];  // H*H + H
    float* sb = sW + H * H;
    for (int i = threadIdx.x; i < H * H; i += 256) sW[i] = W2[i];
    for (int i = threadIdx.x; i < H; i += 256) sb[i] = b1[i];
    __syncthreads();
    int v = blockIdx.x * 256 + threadIdx.x;
    if (v >= V) return;
    i64 m = (i64)blockIdx.y * V + v;
    float di = dinv[v];
    float h[64];
    for (int k = 0; k < H; ++k) h[k] = lrelu(di * Q[m * H + k] + sb[k]);
    for (int f = 0; f < H; ++f) {
        float a = 0.f;
        for (int k = 0; k < H; ++k) a += h[k] * sW[k * H + f];
        float g = di * a;
        P[m * H + f] = __float2bfloat16(g);
        Q[m * H + f] = g;
    }
}

__global__ __launch_bounds__(256) void k_l3_g(const float* __restrict__ W3,
                                              const float* __restrict__ b2,
                                              const float* __restrict__ dinv,
                                              float* __restrict__ R,
                                              const float* __restrict__ Q, int V, int H) {
    extern __shared__ float sW[];  // H*3 + H
    float* sb = sW + H * 3;
    for (int i = threadIdx.x; i < H * 3; i += 256) sW[i] = W3[i];
    for (int i = threadIdx.x; i < H; i += 256) sb[i] = b2[i];
    __syncthreads();
    int v = blockIdx.x * 256 + threadIdx.x;
    if (v >= V) return;
    i64 m = (i64)blockIdx.y * V + v;
    float di = dinv[v];
    float g0 = 0.f, g1 = 0.f, g2 = 0.f;
    for (int k = 0; k < H; ++k) {
        float h = lrelu(di * Q[m * H + k] + sb[k]);
        g0 += h * sW[k * 3]; g1 += h * sW[k * 3 + 1]; g2 += h * sW[k * 3 + 2];
    }
    ((float4*)R)[m] = make_float4(di * g0, di * g1, di * g2, 0.f);
}

// generic-H tail: plain per-batch gather versions (reuse MB=4 kernels with CBc batches)
__global__ __launch_bounds__(256) void k_gvert_g(const int* __restrict__ rowptr,
                                                 const int* __restrict__ col,
                                                 const float* __restrict__ x,
                                                 const float* __restrict__ b3,
                                                 const float* __restrict__ dinv,
                                                 const float* __restrict__ R,
                                                 float* __restrict__ Vpos,
                                                 float* __restrict__ out0,
                                                 int b0, int V, int E) {
    int v = blockIdx.x * 256 + threadIdx.x;
    if (v >= V) return;
    int b = blockIdx.y;
    i64 vb = (i64)b * V;
    const float4* Rb = (const float4*)R + vb;
    float4 s = Rb[v];
    int r0 = rowptr[v], r1 = rowptr[v + 1];
    for (int j = r0; j < r1; ++j) {
        float4 t = Rb[col[j]];
        s.x += t.x; s.y += t.y; s.z += t.z;
    }
    float di = dinv[v];
    int bg = b0 + b;
    i64 n = (i64)bg * V + v;
    float p0 = x[n * 3]     + di * s.x + b3[0];
    float p1 = x[n * 3 + 1] + di * s.y + b3[1];
    float p2 = x[n * 3 + 2] + di * s.z + b3[2];
    ((float4*)Vpos)[vb + v] = make_float4(p0, p1, p2, 0.f);
    i64 o = ((i64)bg * (V + E) + v) * 3;
    out0[o] = p0; out0[o + 1] = p1; out0[o + 2] = p2;
}

__global__ __launch_bounds__(256) void k_mid_g(const int* __restrict__ edges,
                                               const float* __restrict__ Vpos,
                                               float* __restrict__ out0,
                                               int b0, int V, int E) {
    int e = blockIdx.x * 256 + threadIdx.x;
    if (e >= E) return;
    int s = edges[2 * e], d = edges[2 * e + 1];
    float4 ps = ((const float4*)Vpos)[(i64)blockIdx.y * V + s];
    float4 pd = ((const float4*)Vpos)[(i64)blockIdx.y * V + d];
    i64 o = ((i64)(b0 + blockIdx.y) * (V + E) + V + e) * 3;
    out0[o]     = 0.5f * (ps.x + pd.x);
    out0[o + 1] = 0.5f * (ps.y + pd.y);
    out0[o + 2] = 0.5f * (ps.z + pd.z);
}

extern "C" void kernel_launch(void* const* d_in, const int* in_sizes, int n_in,
                              void* d_out, int out_size, void* d_ws, size_t ws_size,
                              hipStream_t stream) {
    const float* verts = (const float*)d_in[0];
    const int*   edges = (const int*)d_in[1];
    const int*   faces = (const int*)d_in[2];
    const float* W1 = (const float*)d_in[3];
    const float* b1 = (const float*)d_in[4];
    const float* W2 = (const float*)d_in[5];
    const float* b2 = (const float*)d_in[6];
    const float* W3 = (const float*)d_in[7];
    const float* b3 = (const float*)d_in[8];

    // ---- derive actual dims from in_sizes / out_size ----
    const i64 s0 = in_sizes[0];            // 3*B*V
    const i64 E  = in_sizes[1] / 2;
    const i64 F  = in_sizes[2] / 3;
    const int H  = in_sizes[4];            // b1 length
    i64 B = 0;
    const i64 denomB = 3 * (E + F);        // faces broadcast per batch
    if ((i64)out_size > s0 && denomB > 0) {
        i64 Bc = ((i64)out_size - s0) / denomB;
        if (Bc >= 1 && s0 + Bc * denomB == (i64)out_size && s0 % (3 * Bc) == 0) B = Bc;
    }
    if (B == 0) {                          // fallback: faces stored once (not broadcast)
        i64 num = (i64)out_size - s0 - 3 * F;
        if (num > 0 && E > 0 && num % (3 * E) == 0) {
            i64 Bc = num / (3 * E);
            if (Bc >= 1 && s0 % (3 * Bc) == 0) B = Bc;
        }
    }
    if (B == 0) B = 16;                    // last resort
    const i64 V = s0 / (3 * B);

    // ---- workspace layout ----
    const i64 Vp  = (V + 255) & ~255LL;
    const i64 NB1 = Vp >> 8;               // scan block capacity
    const size_t AUX = (size_t)Vp * 4 /*dinv*/ + (size_t)Vp * 4 /*indeg*/
                     + (size_t)(Vp + 256) * 4 /*rowptr*/
                     + (size_t)(NB1 + 256) * 4 /*bsum*/
                     + (size_t)E * 4 /*col*/ + 1024;
    const size_t rowB = (size_t)(6 * H) + 96 + 64;   // buffers/row + slack
    i64 CB = B;
    while (CB > 1 && AUX + (size_t)CB * V * rowB + 8192 > ws_size) CB = (CB + 1) / 2;

    float* ws     = (float*)d_ws;
    float* dinv   = ws;
    int*   indeg  = (int*)(ws + Vp);
    int*   rowptr = indeg + Vp;
    int*   bsum   = rowptr + Vp + 256;
    int*   col    = bsum + NB1 + 256;
    char*  base   = (char*)(((size_t)(col + E) + 255) & ~(size_t)255);
    auto pad = [](size_t x) { return (x + 255) & ~(size_t)255; };

    bf16 *PB = nullptr, *Pg = nullptr;
    float *Q, *R, *Vb;
    {
        char* p = base;
        if (H == 16) {
            PB = (bf16*)p;  p += pad((size_t)CB * V * 32);
            Q  = (float*)p; p += pad((size_t)CB * V * 64);
        } else {
            Pg = (bf16*)p;  p += pad((size_t)CB * V * 2 * H);
            Q  = (float*)p; p += pad((size_t)CB * V * 4 * H);
        }
        R  = (float*)p; p += pad((size_t)CB * V * 16);
        Vb = (float*)p;
    }

    const unsigned NBv = (unsigned)((V + 255) / 256);
    const unsigned NBe = (unsigned)((E + 255) / 256);

    // ---- degrees + CSR (batch-invariant, built once) ----
    hipMemsetAsync(indeg, 0, V * sizeof(int), stream);
    if (NBe) k_deg<<<dim3(NBe), 256, 0, stream>>>(edges, indeg, (int)E);
    k_dinv<<<dim3(NBv), 256, 0, stream>>>(indeg, dinv, (int)V);
    k_scan1<<<dim3(NBv), 256, 0, stream>>>(indeg, rowptr, bsum, (int)V);
    k_scan2<<<dim3(1), 1024, 0, stream>>>(bsum, (int)NBv);
    k_scan3<<<dim3(NBv), 256, 0, stream>>>(rowptr, bsum, (int)V, (int)E);
    hipMemsetAsync(indeg, 0, V * sizeof(int), stream);  // reuse as fill cursor
    if (NBe) k_fill<<<dim3(NBe), 256, 0, stream>>>(edges, rowptr, indeg, col, (int)E);

    float* out0 = (float*)d_out;
    const i64 vertElems = B * (V + E) * 3;
    float* out1 = out0 + vertElems;
    const i64 faceElems = (i64)out_size - vertElems;

    for (i64 b0 = 0; b0 < B; b0 += CB) {
        const i64 CBc = (B - b0 < CB) ? (B - b0) : CB;
        if (H == 16) {
            const unsigned NG = (unsigned)((CBc + 3) / 4);
            dim3 gn(NBv, NG);
            dim3 ge(NBe, NG);
            k_gl12<<<gn, 256, 0, stream>>>(rowptr, col, verts, W1, b1, W2, dinv,
                                           PB, Q, (int)b0, (int)V, (int)CBc);
            k_gl3<<<gn, 256, 0, stream>>>(rowptr, col, W3, b2, dinv, PB, Q, R,
                                          (int)V, (int)CBc);
            k_gvert<<<gn, 256, 0, stream>>>(rowptr, col, verts, b3, dinv, R, Vb, out0,
                                            (int)b0, (int)V, (int)E, (int)CBc);
            if (NBe) k_mid<<<ge, 256, 0, stream>>>(edges, Vb, out0, (int)b0, (int)V,
                                                   (int)E, (int)CBc);
        } else {
            dim3 gn(NBv, (unsigned)CBc);
            dim3 ge(NBe, (unsigned)CBc);
            size_t sh1 = (size_t)3 * H * 4;
            size_t sh2 = ((size_t)H * H + H) * 4;
            size_t sh3 = ((size_t)H * 3 + H) * 4;
            k_l1_g<<<gn, 256, sh1, stream>>>(verts, W1, dinv, Pg, Q, (int)b0, (int)V, H);
            if (NBe) k_scatter_g<<<ge, 256, 0, stream>>>(edges, Pg, Q, (int)E, (int)V, H);
            k_l2_g<<<gn, 256, sh2, stream>>>(W2, b1, dinv, Pg, Q, (int)V, H);
            if (NBe) k_scatter_g<<<ge, 256, 0, stream>>>(edges, Pg, Q, (int)E, (int)V, H);
            k_l3_g<<<gn, 256, sh3, stream>>>(W3, b2, dinv, R, Q, (int)V, H);
            k_gvert_g<<<gn, 256, 0, stream>>>(rowptr, col, verts, b3, dinv, R, Vb, out0,
                                              (int)b0, (int)V, (int)E);
            if (NBe) k_mid_g<<<ge, 256, 0, stream>>>(edges, Vb, out0, (int)b0, (int)V,
                                                     (int)E);
        }
    }
    const i64 F3 = 3 * F;
    if (faceElems > 0 && F3 > 0)
        k_faces<<<dim3((unsigned)((F3 + 255) / 256), (unsigned)B), 256, 0, stream>>>(
            faces, out1, F3, faceElems);
}

// Round 7
// 503.997 us; speedup vs baseline: 1.3613x; 1.3613x over previous
//
#include <hip/hip_runtime.h>
#include <hip/hip_bf16.h>

#define NEG_SLOPE 0.01f

typedef long long i64;
typedef __hip_bfloat16 bf16;

__device__ __forceinline__ float lrelu(float x) { return x > 0.f ? x : NEG_SLOPE * x; }
__device__ __forceinline__ float b2f(bf16 v) { return __bfloat162float(v); }
__device__ __forceinline__ float lo2f(unsigned u) { return __uint_as_float(u << 16); }
__device__ __forceinline__ float hi2f(unsigned u) { return __uint_as_float(u & 0xffff0000u); }
__device__ __forceinline__ unsigned pk2(float a, float b) {
    unsigned ua = __bfloat16_as_ushort(__float2bfloat16(a));
    unsigned ub = __bfloat16_as_ushort(__float2bfloat16(b));
    return ua | (ub << 16);
}
__device__ __forceinline__ void acc8(float* h, uint4 u) {
    h[0] += lo2f(u.x); h[1] += hi2f(u.x);
    h[2] += lo2f(u.y); h[3] += hi2f(u.y);
    h[4] += lo2f(u.z); h[5] += hi2f(u.z);
    h[6] += lo2f(u.w); h[7] += hi2f(u.w);
}

// XCD-aware decode: pin batch b to XCD (wgid&7) so each XCD's gather slice is
// L2-resident. Bijective for CBc%8==0; plain decode otherwise.
__device__ __forceinline__ void decode_bxb(int wg, int NB, int CBc, int& b, int& xb) {
    if ((CBc & 7) == 0) {
        int xcd = wg & 7, k = wg >> 3;
        int bl = k / NB;
        xb = k - bl * NB;
        b = xcd + 8 * bl;
    } else {
        b = wg / NB;
        xb = wg - b * NB;
    }
}

// ================= degree / dinv (batch-independent) =================
__global__ __launch_bounds__(256) void k_deg(const int* __restrict__ edges,
                                             int* __restrict__ indeg, int E) {
    int e = blockIdx.x * 256 + threadIdx.x;
    if (e < E) atomicAdd(&indeg[edges[2 * e + 1]], 1);
}

// ================= CSR build: exclusive scan of indeg + fill =================
// scan1 also emits dinv (free fusion: it already reads indeg)
__global__ __launch_bounds__(256) void k_scan1(const int* __restrict__ indeg,
                                               int* __restrict__ rowptr,
                                               int* __restrict__ bsum,
                                               float* __restrict__ dinv, int V) {
    __shared__ int s[256];
    int i = blockIdx.x * 256 + threadIdx.x;
    int x = (i < V) ? indeg[i] : 0;
    if (i < V) dinv[i] = rsqrtf((float)x + 1.0f);
    s[threadIdx.x] = x;
    __syncthreads();
    for (int off = 1; off < 256; off <<= 1) {
        int t = (threadIdx.x >= (unsigned)off) ? s[threadIdx.x - off] : 0;
        __syncthreads();
        s[threadIdx.x] += t;
        __syncthreads();
    }
    if (i < V) rowptr[i] = s[threadIdx.x] - x;  // exclusive within block
    if (threadIdx.x == 255) bsum[blockIdx.x] = s[255];
}

__global__ __launch_bounds__(1024) void k_scan2(int* __restrict__ bsum, int NB) {
    __shared__ int s[1024];
    __shared__ int srun;
    if (threadIdx.x == 0) srun = 0;
    __syncthreads();
    for (int base = 0; base < NB; base += 1024) {
        int i = base + threadIdx.x;
        int x = (i < NB) ? bsum[i] : 0;
        s[threadIdx.x] = x;
        __syncthreads();
        for (int off = 1; off < 1024; off <<= 1) {
            int t = (threadIdx.x >= (unsigned)off) ? s[threadIdx.x - off] : 0;
            __syncthreads();
            s[threadIdx.x] += t;
            __syncthreads();
        }
        int run = srun;
        if (i < NB) bsum[i] = run + s[threadIdx.x] - x;  // exclusive
        __syncthreads();
        if (threadIdx.x == 1023) srun = run + s[1023];
        __syncthreads();
    }
}

__global__ __launch_bounds__(256) void k_scan3(int* __restrict__ rowptr,
                                               const int* __restrict__ bsum,
                                               int V, int E) {
    int i = blockIdx.x * 256 + threadIdx.x;
    if (i < V) rowptr[i] += bsum[blockIdx.x];
    if (i == 0) rowptr[V] = E;
}

__global__ __launch_bounds__(256) void k_rp2(const int* __restrict__ rowptr,
                                             int2* __restrict__ rp2, int V) {
    int v = blockIdx.x * 256 + threadIdx.x;
    if (v < V) rp2[v] = make_int2(rowptr[v], rowptr[v + 1]);
}

__global__ __launch_bounds__(256) void k_fill(const int* __restrict__ edges,
                                              const int* __restrict__ rowptr,
                                              int* __restrict__ cur,
                                              int* __restrict__ col, int E) {
    int e = blockIdx.x * 256 + threadIdx.x;
    if (e >= E) return;
    int s = edges[2 * e], d = edges[2 * e + 1];
    int p = atomicAdd(&cur[d], 1);
    col[rowptr[d] + p] = s;
}

// ========== H==16: fused layer1+layer2, per-batch, linearity trick ==========
// h1_pre = di * ((Σ_{u∈{v}∪N(v)} du·x_u) @ W1)   (layer-1 is linear pre-lrelu)
__global__ __launch_bounds__(256) void k_gl12(const int2* __restrict__ rp2,
                                              const int* __restrict__ col,
                                              const float* __restrict__ verts,
                                              const float* __restrict__ W1,
                                              const float* __restrict__ b1,
                                              const float* __restrict__ W2,
                                              const float* __restrict__ dinv,
                                              bf16* __restrict__ PB,
                                              float* __restrict__ Q,
                                              int b0, int V, int NB, int CBc) {
    int b, xb;
    decode_bxb(blockIdx.x, NB, CBc, b, xb);
    int v = xb * 256 + threadIdx.x;
    if (v >= V) return;
    i64 vg = (i64)(b0 + b) * V;   // global verts base
    i64 vb = (i64)b * V;          // workspace base
    float di = dinv[v];
    const float* xv = verts + (vg + v) * 3;
    float c0 = di * xv[0], c1 = di * xv[1], c2 = di * xv[2];
    int2 r = rp2[v];
    int j = r.x;
    for (; j + 1 < r.y; j += 2) {
        int s0 = col[j], s1 = col[j + 1];
        float d0 = dinv[s0], d1 = dinv[s1];
        const float* p0 = verts + (vg + s0) * 3;
        const float* p1 = verts + (vg + s1) * 3;
        c0 += d0 * p0[0] + d1 * p1[0];
        c1 += d0 * p0[1] + d1 * p1[1];
        c2 += d0 * p0[2] + d1 * p1[2];
    }
    if (j < r.y) {
        int s0 = col[j];
        float d0 = dinv[s0];
        const float* p0 = verts + (vg + s0) * 3;
        c0 += d0 * p0[0]; c1 += d0 * p0[1]; c2 += d0 * p0[2];
    }
    float h[16];
#pragma unroll
    for (int f = 0; f < 16; ++f)
        h[f] = lrelu(di * (c0 * W1[f] + c1 * W1[16 + f] + c2 * W1[32 + f]) + b1[f]);
    float g[16];
#pragma unroll
    for (int f = 0; f < 16; ++f) g[f] = 0.f;
#pragma unroll
    for (int k = 0; k < 16; ++k) {
        float hk = h[k];
#pragma unroll
        for (int f = 0; f < 16; ++f) g[f] += hk * W2[k * 16 + f];
    }
#pragma unroll
    for (int f = 0; f < 16; ++f) g[f] *= di;
    i64 m = vb + v;
    uint4* Pp = (uint4*)(PB + m * 16);
    Pp[0] = make_uint4(pk2(g[0], g[1]), pk2(g[2], g[3]), pk2(g[4], g[5]), pk2(g[6], g[7]));
    Pp[1] = make_uint4(pk2(g[8], g[9]), pk2(g[10], g[11]), pk2(g[12], g[13]), pk2(g[14], g[15]));
    float4* Qp = (float4*)(Q + m * 16);
#pragma unroll
    for (int q = 0; q < 4; ++q)
        Qp[q] = make_float4(g[4 * q], g[4 * q + 1], g[4 * q + 2], g[4 * q + 3]);
}

// ========== H==16: fused gather + layer3 (16 -> 3) ==========
__global__ __launch_bounds__(256) void k_gl3(const int2* __restrict__ rp2,
                                             const int* __restrict__ col,
                                             const float* __restrict__ W3,
                                             const float* __restrict__ b2,
                                             const float* __restrict__ dinv,
                                             const bf16* __restrict__ Pin,
                                             const float* __restrict__ Q,
                                             float* __restrict__ R,
                                             int V, int NB, int CBc) {
    int b, xb;
    decode_bxb(blockIdx.x, NB, CBc, b, xb);
    int v = xb * 256 + threadIdx.x;
    if (v >= V) return;
    i64 vb = (i64)b * V;
    i64 m = vb + v;
    float h[16];
    const float4* Qin = (const float4*)(Q + m * 16);
#pragma unroll
    for (int q = 0; q < 4; ++q) {
        float4 t = Qin[q];
        h[4 * q] = t.x; h[4 * q + 1] = t.y; h[4 * q + 2] = t.z; h[4 * q + 3] = t.w;
    }
    const uint4* Pb = (const uint4*)(Pin + vb * 16);
    int2 r = rp2[v];
    int j = r.x;
    for (; j + 1 < r.y; j += 2) {
        size_t u0 = (size_t)col[j] * 2, u1 = (size_t)col[j + 1] * 2;
        uint4 q0 = Pb[u0], q1 = Pb[u0 + 1];
        uint4 c0 = Pb[u1], c1 = Pb[u1 + 1];
        acc8(h, q0); acc8(h + 8, q1);
        acc8(h, c0); acc8(h + 8, c1);
    }
    if (j < r.y) {
        size_t u0 = (size_t)col[j] * 2;
        uint4 q0 = Pb[u0], q1 = Pb[u0 + 1];
        acc8(h, q0); acc8(h + 8, q1);
    }
    float di = dinv[v];
    float g0 = 0.f, g1 = 0.f, g2 = 0.f;
#pragma unroll
    for (int k = 0; k < 16; ++k) {
        float hk = lrelu(di * h[k] + b2[k]);
        g0 += hk * W3[k * 3 + 0];
        g1 += hk * W3[k * 3 + 1];
        g2 += hk * W3[k * 3 + 2];
    }
    ((float4*)R)[m] = make_float4(di * g0, di * g1, di * g2, 0.f);
}

// fused gather + final vertex update (H-independent): sums R over in-edges.
__global__ __launch_bounds__(256) void k_gvert(const int2* __restrict__ rp2,
                                               const int* __restrict__ col,
                                               const float* __restrict__ x,
                                               const float* __restrict__ b3,
                                               const float* __restrict__ dinv,
                                               const float* __restrict__ R,
                                               float* __restrict__ Vpos,
                                               float* __restrict__ out0,
                                               int b0, int V, int E, int NB, int CBc) {
    int b, xb;
    decode_bxb(blockIdx.x, NB, CBc, b, xb);
    int v = xb * 256 + threadIdx.x;
    if (v >= V) return;
    i64 vb = (i64)b * V;
    i64 m = vb + v;
    const float4* Rb = (const float4*)R + vb;
    float4 s = Rb[v];
    int2 r = rp2[v];
    int j = r.x;
    for (; j + 1 < r.y; j += 2) {
        float4 t0 = Rb[col[j]];
        float4 t1 = Rb[col[j + 1]];
        s.x += t0.x + t1.x; s.y += t0.y + t1.y; s.z += t0.z + t1.z;
    }
    if (j < r.y) {
        float4 t0 = Rb[col[j]];
        s.x += t0.x; s.y += t0.y; s.z += t0.z;
    }
    float di = dinv[v];
    int bg = b0 + b;
    i64 n = (i64)bg * V + v;
    float p0 = x[n * 3]     + di * s.x + b3[0];
    float p1 = x[n * 3 + 1] + di * s.y + b3[1];
    float p2 = x[n * 3 + 2] + di * s.z + b3[2];
    ((float4*)Vpos)[m] = make_float4(p0, p1, p2, 0.f);
    i64 o = ((i64)bg * (V + E) + v) * 3;
    __builtin_nontemporal_store(p0, out0 + o);
    __builtin_nontemporal_store(p1, out0 + o + 1);
    __builtin_nontemporal_store(p2, out0 + o + 2);
}

__global__ __launch_bounds__(256) void k_mid(const int* __restrict__ edges,
                                             const float* __restrict__ Vpos,
                                             float* __restrict__ out0,
                                             int b0, int V, int E, int NB, int CBc) {
    int b, xe;
    decode_bxb(blockIdx.x, NB, CBc, b, xe);
    int e = xe * 256 + threadIdx.x;
    if (e >= E) return;
    int2 sd = ((const int2*)edges)[e];
    float4 ps = ((const float4*)Vpos)[(i64)b * V + sd.x];
    float4 pd = ((const float4*)Vpos)[(i64)b * V + sd.y];
    i64 o = ((i64)(b0 + b) * (V + E) + V + e) * 3;
    __builtin_nontemporal_store(0.5f * (ps.x + pd.x), out0 + o);
    __builtin_nontemporal_store(0.5f * (ps.y + pd.y), out0 + o + 1);
    __builtin_nontemporal_store(0.5f * (ps.z + pd.z), out0 + o + 2);
}

__global__ __launch_bounds__(256) void k_faces(const int* __restrict__ faces,
                                               float* __restrict__ out1,
                                               i64 F3, i64 faceElems) {
    i64 i = (i64)blockIdx.x * 256 + threadIdx.x;
    if (i >= F3) return;
    i64 o = (i64)blockIdx.y * F3 + i;
    if (o < faceElems) __builtin_nontemporal_store((float)faces[i], out1 + o);
}

// vectorized faces: requires F3 % 4 == 0 and out1 16B-aligned.
// scalar nontemporal stores to consecutive addrs merge into dwordx4 nt.
__global__ __launch_bounds__(256) void k_faces4(const int4* __restrict__ faces4,
                                                float* __restrict__ out1,
                                                i64 Fq, i64 F3) {
    i64 t = (i64)blockIdx.x * 256 + threadIdx.x;
    if (t >= Fq) return;
    int4 u = faces4[t];
    float* p = out1 + (i64)blockIdx.y * F3 + t * 4;
    __builtin_nontemporal_store((float)u.x, p);
    __builtin_nontemporal_store((float)u.y, p + 1);
    __builtin_nontemporal_store((float)u.z, p + 2);
    __builtin_nontemporal_store((float)u.w, p + 3);
}

// ================= generic H path (correctness fallback, H <= 64) =================
__global__ __launch_bounds__(256) void k_dinv_g(const int* __restrict__ indeg,
                                                float* __restrict__ dinv, int V) {
    int v = blockIdx.x * 256 + threadIdx.x;
    if (v < V) dinv[v] = rsqrtf((float)indeg[v] + 1.0f);
}

__global__ __launch_bounds__(256) void k_l1_g(const float* __restrict__ x,
                                              const float* __restrict__ W1,
                                              const float* __restrict__ dinv,
                                              bf16* __restrict__ P, float* __restrict__ Q,
                                              int b0, int V, int H) {
    extern __shared__ float sW[];
    for (int i = threadIdx.x; i < 3 * H; i += 256) sW[i] = W1[i];
    __syncthreads();
    int v = blockIdx.x * 256 + threadIdx.x;
    if (v >= V) return;
    i64 n = (i64)(b0 + blockIdx.y) * V + v;
    i64 m = (i64)blockIdx.y * V + v;
    float di = dinv[v];
    float x0 = x[n * 3], x1 = x[n * 3 + 1], x2 = x[n * 3 + 2];
    for (int f = 0; f < H; ++f) {
        float g = di * (x0 * sW[f] + x1 * sW[H + f] + x2 * sW[2 * H + f]);
        P[m * H + f] = __float2bfloat16(g);
        Q[m * H + f] = g;
    }
}

__global__ __launch_bounds__(256) void k_scatter_g(const int* __restrict__ edges,
                                                   const bf16* __restrict__ P,
                                                   float* __restrict__ Q,
                                                   int E, int V, int H) {
    int e = blockIdx.x * 256 + threadIdx.x;
    if (e >= E) return;
    int b = blockIdx.y;
    int s = edges[2 * e], d = edges[2 * e + 1];
    for (int f = 0; f < H; ++f)
        unsafeAtomicAdd(&Q[((i64)b * V + d) * H + f], b2f(P[((i64)b * V + s) * H + f]));
}

__global__ __launch_bounds__(256) void k_l2_g(const float* __restrict__ W2,
                                              const float* __restrict__ b1,
                                              const float* __restrict__ dinv,
                                              bf16* __restrict__ P, float* __restrict__ Q,
                                              int V, int H) {
    extern __shared__ float sW[];  // H*H + H
    float* sb = sW + H * H;
    for (int i = threadIdx.x; i < H * H; i += 256) sW[i] = W2[i];
    for (int i = threadIdx.x; i < H; i += 256) sb[i] = b1[i];
    __syncthreads();
    int v = blockIdx.x * 256 + threadIdx.x;
    if (v >= V) return;
    i64 m = (i64)blockIdx.y * V + v;
    float di = dinv[v];
    float h[64];
    for (int k = 0; k < H; ++k) h[k] = lrelu(di * Q[m * H + k] + sb[k]);
    for (int f = 0; f < H; ++f) {
        float a = 0.f;
        for (int k = 0; k < H; ++k) a += h[k] * sW[k * H + f];
        float g = di * a;
        P[m * H + f] = __float2bfloat16(g);
        Q[m * H + f] = g;
    }
}

__global__ __launch_bounds__(256) void k_l3_g(const float* __restrict__ W3,
                                              const float* __restrict__ b2,
                                              const float* __restrict__ dinv,
                                              float* __restrict__ R,
                                              const float* __restrict__ Q, int V, int H) {
    extern __shared__ float sW[];  // H*3 + H
    float* sb = sW + H * 3;
    for (int i = threadIdx.x; i < H * 3; i += 256) sW[i] = W3[i];
    for (int i = threadIdx.x; i < H; i += 256) sb[i] = b2[i];
    __syncthreads();
    int v = blockIdx.x * 256 + threadIdx.x;
    if (v >= V) return;
    i64 m = (i64)blockIdx.y * V + v;
    float di = dinv[v];
    float g0 = 0.f, g1 = 0.f, g2 = 0.f;
    for (int k = 0; k < H; ++k) {
        float h = lrelu(di * Q[m * H + k] + sb[k]);
        g0 += h * sW[k * 3]; g1 += h * sW[k * 3 + 1]; g2 += h * sW[k * 3 + 2];
    }
    ((float4*)R)[m] = make_float4(di * g0, di * g1, di * g2, 0.f);
}

extern "C" void kernel_launch(void* const* d_in, const int* in_sizes, int n_in,
                              void* d_out, int out_size, void* d_ws, size_t ws_size,
                              hipStream_t stream) {
    const float* verts = (const float*)d_in[0];
    const int*   edges = (const int*)d_in[1];
    const int*   faces = (const int*)d_in[2];
    const float* W1 = (const float*)d_in[3];
    const float* b1 = (const float*)d_in[4];
    const float* W2 = (const float*)d_in[5];
    const float* b2 = (const float*)d_in[6];
    const float* W3 = (const float*)d_in[7];
    const float* b3 = (const float*)d_in[8];

    // ---- derive actual dims from in_sizes / out_size ----
    const i64 s0 = in_sizes[0];            // 3*B*V
    const i64 E  = in_sizes[1] / 2;
    const i64 F  = in_sizes[2] / 3;
    const int H  = in_sizes[4];            // b1 length
    i64 B = 0;
    const i64 denomB = 3 * (E + F);        // faces broadcast per batch
    if ((i64)out_size > s0 && denomB > 0) {
        i64 Bc = ((i64)out_size - s0) / denomB;
        if (Bc >= 1 && s0 + Bc * denomB == (i64)out_size && s0 % (3 * Bc) == 0) B = Bc;
    }
    if (B == 0) {                          // fallback: faces stored once (not broadcast)
        i64 num = (i64)out_size - s0 - 3 * F;
        if (num > 0 && E > 0 && num % (3 * E) == 0) {
            i64 Bc = num / (3 * E);
            if (Bc >= 1 && s0 % (3 * Bc) == 0) B = Bc;
        }
    }
    if (B == 0) B = 16;                    // last resort
    const i64 V = s0 / (3 * B);

    // ---- workspace layout ----
    const i64 Vp  = (V + 255) & ~255LL;
    const i64 NB1 = Vp >> 8;               // scan block capacity
    const size_t AUX = (size_t)Vp * 4 /*dinv*/ + (size_t)Vp * 4 /*indeg*/
                     + (size_t)(Vp + 256) * 4 /*rowptr*/
                     + (size_t)(NB1 + 256) * 4 /*bsum*/
                     + (size_t)Vp * 8 /*rp2*/
                     + (size_t)E * 4 /*col*/ + 1024;
    const size_t rowB = (size_t)(6 * H) + 96 + 64;   // buffers/row + slack
    i64 CB = B;
    while (CB > 1 && AUX + (size_t)CB * V * rowB + 8192 > ws_size) CB = (CB + 1) / 2;

    float* ws     = (float*)d_ws;
    float* dinv   = ws;
    int*   indeg  = (int*)(ws + Vp);
    int*   rowptr = indeg + Vp;
    int*   bsum   = rowptr + Vp + 256;
    int2*  rp2    = (int2*)(bsum + NB1 + 256);
    int*   col    = (int*)(rp2 + Vp);
    char*  base   = (char*)(((size_t)(col + E) + 255) & ~(size_t)255);
    auto pad = [](size_t x) { return (x + 255) & ~(size_t)255; };

    bf16 *PB = nullptr, *Pg = nullptr;
    float *Q, *R, *Vb;
    {
        char* p = base;
        if (H == 16) {
            PB = (bf16*)p;  p += pad((size_t)CB * V * 32);
            Q  = (float*)p; p += pad((size_t)CB * V * 64);
        } else {
            Pg = (bf16*)p;  p += pad((size_t)CB * V * 2 * H);
            Q  = (float*)p; p += pad((size_t)CB * V * 4 * H);
        }
        R  = (float*)p; p += pad((size_t)CB * V * 16);
        Vb = (float*)p;
    }

    const unsigned NBv = (unsigned)((V + 255) / 256);
    const unsigned NBe = (unsigned)((E + 255) / 256);

    // ---- degrees + CSR (batch-invariant, built once) ----
    hipMemsetAsync(indeg, 0, V * sizeof(int), stream);
    if (NBe) k_deg<<<dim3(NBe), 256, 0, stream>>>(edges, indeg, (int)E);
    k_scan1<<<dim3(NBv), 256, 0, stream>>>(indeg, rowptr, bsum, dinv, (int)V);
    k_scan2<<<dim3(1), 1024, 0, stream>>>(bsum, (int)NBv);
    k_scan3<<<dim3(NBv), 256, 0, stream>>>(rowptr, bsum, (int)V, (int)E);
    k_rp2<<<dim3(NBv), 256, 0, stream>>>(rowptr, rp2, (int)V);
    hipMemsetAsync(indeg, 0, V * sizeof(int), stream);  // reuse as fill cursor
    if (NBe) k_fill<<<dim3(NBe), 256, 0, stream>>>(edges, rowptr, indeg, col, (int)E);

    float* out0 = (float*)d_out;
    const i64 vertElems = B * (V + E) * 3;
    float* out1 = out0 + vertElems;
    const i64 faceElems = (i64)out_size - vertElems;

    for (i64 b0 = 0; b0 < B; b0 += CB) {
        const i64 CBc = (B - b0 < CB) ? (B - b0) : CB;
        dim3 g1((unsigned)(NBv * CBc));
        dim3 g1e((unsigned)(NBe * CBc));
        if (H == 16) {
            k_gl12<<<g1, 256, 0, stream>>>(rp2, col, verts, W1, b1, W2, dinv,
                                           PB, Q, (int)b0, (int)V, (int)NBv, (int)CBc);
            k_gl3<<<g1, 256, 0, stream>>>(rp2, col, W3, b2, dinv, PB, Q, R,
                                          (int)V, (int)NBv, (int)CBc);
        } else {
            dim3 gn(NBv, (unsigned)CBc);
            dim3 ge(NBe, (unsigned)CBc);
            size_t sh1 = (size_t)3 * H * 4;
            size_t sh2 = ((size_t)H * H + H) * 4;
            size_t sh3 = ((size_t)H * 3 + H) * 4;
            k_l1_g<<<gn, 256, sh1, stream>>>(verts, W1, dinv, Pg, Q, (int)b0, (int)V, H);
            if (NBe) k_scatter_g<<<ge, 256, 0, stream>>>(edges, Pg, Q, (int)E, (int)V, H);
            k_l2_g<<<gn, 256, sh2, stream>>>(W2, b1, dinv, Pg, Q, (int)V, H);
            if (NBe) k_scatter_g<<<ge, 256, 0, stream>>>(edges, Pg, Q, (int)E, (int)V, H);
            k_l3_g<<<gn, 256, sh3, stream>>>(W3, b2, dinv, R, Q, (int)V, H);
        }
        k_gvert<<<g1, 256, 0, stream>>>(rp2, col, verts, b3, dinv, R, Vb, out0,
                                        (int)b0, (int)V, (int)E, (int)NBv, (int)CBc);
        if (NBe) k_mid<<<g1e, 256, 0, stream>>>(edges, Vb, out0, (int)b0, (int)V, (int)E,
                                                (int)NBe, (int)CBc);
    }
    const i64 F3 = 3 * F;
    if (faceElems > 0 && F3 > 0) {
        bool v4 = ((F3 & 3) == 0) && ((vertElems & 3) == 0) && (faceElems == B * F3);
        if (v4) {
            const i64 Fq = F3 >> 2;
            k_faces4<<<dim3((unsigned)((Fq + 255) / 256), (unsigned)B), 256, 0, stream>>>(
                (const int4*)faces, out1, Fq, F3);
        } else {
            k_faces<<<dim3((unsigned)((F3 + 255) / 256), (unsigned)B), 256, 0, stream>>>(
                faces, out1, F3, faceElems);
        }
    }
}